// Round 1
// baseline (4558.242 us; speedup 1.0000x reference)
//
#include <hip/hip_runtime.h>
#include <math.h>

// Problem constants (from reference)
#define LNUM 8
#define ENUM 8
#define RNUM 64
#define HNUM 2048
#define TNUM 8192                    // BSZ*SEQ
#define SLICE (TNUM*HNUM)            // one hidden_states slice
#define M1 16                        // tokens per block, mix/gate kernel
#define M2 16                        // tokens per GEMM tile (expert-uniform)
#define PADT (TNUM + ENUM*M2)        // 8320: per-expert segments padded to M2
#define KHALF (HNUM/2)               // gemmA K-split

// ---------------------------------------------------------------------------
// Kernel 1: x = z*x + (1-z)*h_x; gate logits (double-reduced), softmax top-1.
// One block = 16 tokens, 256 threads. Writes mixed x to xbuf, g/coef, counts.
// ---------------------------------------------------------------------------
__global__ __launch_bounds__(256) void mix_gate_kernel(
    const float* __restrict__ xsrc, const float* __restrict__ hx,
    const float* __restrict__ gates, int layer,
    const float* __restrict__ gw,          // [E][H]
    float* __restrict__ xbuf, int* __restrict__ g_idx,
    float* __restrict__ coefp, int* __restrict__ cnt)
{
    __shared__ double wred[4][ENUM];
    const int tid  = threadIdx.x;
    const int wave = tid >> 6, lane = tid & 63;
    const float gv = gates[layer];
    const float z  = 1.0f / (1.0f + expf(-gv));
    const float zo = 1.0f - z;
    const float4* gw4 = (const float4*)gw;

    for (int m = 0; m < M1; ++m) {
        const int t = blockIdx.x * M1 + m;
        const size_t b4 = (size_t)t * (HNUM/4);
        float4 xa0 = ((const float4*)xsrc)[b4 + tid];
        float4 xa1 = ((const float4*)xsrc)[b4 + tid + 256];
        float4 xb0 = ((const float4*)hx)[b4 + tid];
        float4 xb1 = ((const float4*)hx)[b4 + tid + 256];
        float4 v0, v1;
        v0.x = z*xa0.x + zo*xb0.x;  v0.y = z*xa0.y + zo*xb0.y;
        v0.z = z*xa0.z + zo*xb0.z;  v0.w = z*xa0.w + zo*xb0.w;
        v1.x = z*xa1.x + zo*xb1.x;  v1.y = z*xa1.y + zo*xb1.y;
        v1.z = z*xa1.z + zo*xb1.z;  v1.w = z*xa1.w + zo*xb1.w;
        ((float4*)xbuf)[b4 + tid]       = v0;
        ((float4*)xbuf)[b4 + tid + 256] = v1;

        // per-thread partial logits (8 elems each), then double tree-reduce:
        // keeps logit error ~1e-7 so top-1 matches the numpy reference.
        double dl[ENUM];
        #pragma unroll
        for (int e = 0; e < ENUM; ++e) {
            float4 g0 = gw4[e*(HNUM/4) + tid];
            float4 g1 = gw4[e*(HNUM/4) + tid + 256];
            float pl = v0.x*g0.x + v0.y*g0.y + v0.z*g0.z + v0.w*g0.w
                     + v1.x*g1.x + v1.y*g1.y + v1.z*g1.z + v1.w*g1.w;
            dl[e] = (double)pl;
        }
        #pragma unroll
        for (int off = 32; off >= 1; off >>= 1) {
            #pragma unroll
            for (int e = 0; e < ENUM; ++e)
                dl[e] += __shfl_down(dl[e], off, 64);
        }
        if (lane == 0) {
            #pragma unroll
            for (int e = 0; e < ENUM; ++e) wred[wave][e] = dl[e];
        }
        __syncthreads();
        if (tid == 0) {
            double lg[ENUM];
            #pragma unroll
            for (int e = 0; e < ENUM; ++e)
                lg[e] = wred[0][e] + wred[1][e] + wred[2][e] + wred[3][e];
            int g = 0; double mx = lg[0];
            #pragma unroll
            for (int e = 1; e < ENUM; ++e) if (lg[e] > mx) { mx = lg[e]; g = e; }
            double s = 0.0;
            #pragma unroll
            for (int e = 0; e < ENUM; ++e) s += exp(lg[e] - mx);
            g_idx[t] = g;
            coefp[t] = (float)(0.5 / s);      // SCALING * p_g, p_g = exp(0)/s
            atomicAdd(&cnt[g], 1);
        }
        __syncthreads();
    }
}

// ---------------------------------------------------------------------------
// Kernel 2: scatter tokens into expert-contiguous segments padded to M2.
// perm pre-filled with -1; segment base = sum of padded counts of e' < g.
// ---------------------------------------------------------------------------
__global__ __launch_bounds__(256) void scatter_kernel(
    const int* __restrict__ g_idx, const int* __restrict__ cnt,
    int* __restrict__ ctr, int* __restrict__ perm)
{
    const int t = blockIdx.x * 256 + threadIdx.x;
    const int g = g_idx[t];
    int base = 0;
    #pragma unroll
    for (int e = 0; e < ENUM; ++e) {
        int padded = (cnt[e] + (M2 - 1)) & ~(M2 - 1);
        if (e < g) base += padded;
    }
    const int pos = base + atomicAdd(&ctr[g], 1);
    perm[pos] = t;
}

// ---------------------------------------------------------------------------
// Kernel 3: h[pos][r] = A_e[r][:] . x[t][:]  (expert-uniform 16-token tiles,
// K split in 2 halves across blocks for occupancy; partials summed in gemmB).
// Thread: mq=tid&3 -> 4 tokens (m=4mq+j), rp=tid>>2 -> one r. 4 accs.
// LDS: xs transposed [k][m] (b128 over m, broadcast-friendly); as [r][k].
// ---------------------------------------------------------------------------
__global__ __launch_bounds__(256) void gemmA_kernel(
    const float* __restrict__ xbuf, const float* __restrict__ A_l,  // [E][R][H]
    const int* __restrict__ perm, const int* __restrict__ g_idx,
    float* __restrict__ hbuf)                                       // [2][PADT][R]
{
    const int mt   = blockIdx.x >> 1;
    const int ks   = blockIdx.x & 1;
    const int pos0 = mt * M2;
    __shared__ int   tids[M2];
    __shared__ float xs[64][20];   // [k in chunk][m], row stride 20 keeps b128 aligned
    __shared__ float as[64][68];   // [r][k in chunk]
    const int tid = threadIdx.x;
    if (tid < M2) tids[tid] = perm[pos0 + tid];
    __syncthreads();
    int e = -1;
    #pragma unroll
    for (int m = 0; m < M2; ++m) { int tt = tids[m]; if (e < 0 && tt >= 0) e = g_idx[tt]; }
    if (e < 0) return;                       // fully-padded tile

    const float* Ae = A_l + (size_t)e * RNUM * HNUM + (size_t)ks * KHALF;
    const int mq = tid & 3;
    const int rp = tid >> 2;                 // also the staging row for A
    const int sm  = tid >> 4;                // staging token
    const int sk4 = tid & 15;                // staging k-quad
    const int st  = tids[sm];

    float acc[4] = {0.f, 0.f, 0.f, 0.f};
    for (int ch = 0; ch < 16; ++ch) {
        const int k0 = ch * 64;
        __syncthreads();
        // stage x chunk (transposed): 16m x 64k
        float4 xv = make_float4(0.f, 0.f, 0.f, 0.f);
        if (st >= 0)
            xv = *(const float4*)(xbuf + (size_t)st*HNUM + (size_t)ks*KHALF + k0 + 4*sk4);
        xs[4*sk4+0][sm] = xv.x;
        xs[4*sk4+1][sm] = xv.y;
        xs[4*sk4+2][sm] = xv.z;
        xs[4*sk4+3][sm] = xv.w;
        // stage A chunk: 64r x 64k, 64B contiguous per thread
        {
            const float* src = Ae + (size_t)rp*HNUM + k0 + mq*16;
            float4 a0 = ((const float4*)src)[0];
            float4 a1 = ((const float4*)src)[1];
            float4 a2 = ((const float4*)src)[2];
            float4 a3 = ((const float4*)src)[3];
            float* dst = &as[rp][mq*16];
            ((float4*)dst)[0] = a0; ((float4*)dst)[1] = a1;
            ((float4*)dst)[2] = a2; ((float4*)dst)[3] = a3;
        }
        __syncthreads();
        #pragma unroll
        for (int k4 = 0; k4 < 16; ++k4) {
            float4 a4 = *(const float4*)&as[rp][4*k4];
            float4 x0 = *(const float4*)&xs[4*k4+0][4*mq];
            float4 x1 = *(const float4*)&xs[4*k4+1][4*mq];
            float4 x2 = *(const float4*)&xs[4*k4+2][4*mq];
            float4 x3 = *(const float4*)&xs[4*k4+3][4*mq];
            acc[0] += a4.x*x0.x + a4.y*x1.x + a4.z*x2.x + a4.w*x3.x;
            acc[1] += a4.x*x0.y + a4.y*x1.y + a4.z*x2.y + a4.w*x3.y;
            acc[2] += a4.x*x0.z + a4.y*x1.z + a4.z*x2.z + a4.w*x3.z;
            acc[3] += a4.x*x0.w + a4.y*x1.w + a4.z*x2.w + a4.w*x3.w;
        }
    }
    float* hp = hbuf + ((size_t)ks*PADT + pos0) * RNUM;
    #pragma unroll
    for (int j = 0; j < 4; ++j) hp[(size_t)(4*mq + j)*RNUM + rp] = acc[j];
}

// ---------------------------------------------------------------------------
// Kernel 4: y[t][hc] = coef[t] * sum_r h[pos][r] * B_e[hc][r], scattered into
// xbuf rows. Grid: (m-tile, 64-wide hc chunk). Sums the two K-split h halves.
// ---------------------------------------------------------------------------
__global__ __launch_bounds__(256) void gemmB_kernel(
    const float* __restrict__ hbuf, const float* __restrict__ B_l,  // [E][H][R]
    const int* __restrict__ perm, const int* __restrict__ g_idx,
    const float* __restrict__ coefp, float* __restrict__ xbuf)
{
    const int mt   = blockIdx.x >> 5;
    const int hc0  = (blockIdx.x & 31) * 64;
    const int pos0 = mt * M2;
    __shared__ int   tids[M2];
    __shared__ float cof[M2];
    __shared__ float hT[RNUM][20];  // [r][m]
    __shared__ float bs[64][68];    // [hc][r]
    const int tid = threadIdx.x;
    if (tid < M2) {
        int t = perm[pos0 + tid];
        tids[tid] = t;
        cof[tid] = (t >= 0) ? coefp[t] : 0.0f;
    }
    __syncthreads();
    int e = -1;
    #pragma unroll
    for (int m = 0; m < M2; ++m) { int tt = tids[m]; if (e < 0 && tt >= 0) e = g_idx[tt]; }
    if (e < 0) return;
    // stage h (sum K-split halves), transposed to [r][m]
    {
        const int m = tid >> 4, r4 = tid & 15;
        const float* h0 = hbuf + (size_t)(pos0 + m)*RNUM + 4*r4;
        const float* h1 = h0 + (size_t)PADT*RNUM;
        float4 a = *(const float4*)h0;
        float4 b = *(const float4*)h1;
        hT[4*r4+0][m] = a.x + b.x;
        hT[4*r4+1][m] = a.y + b.y;
        hT[4*r4+2][m] = a.z + b.z;
        hT[4*r4+3][m] = a.w + b.w;
    }
    // stage B chunk: 64 rows (hc) x 64 (r)
    {
        const int hc = tid >> 2, kb = (tid & 3) * 16;
        const float* src = B_l + (size_t)e*HNUM*RNUM + (size_t)(hc0 + hc)*RNUM + kb;
        float4 b0 = ((const float4*)src)[0];
        float4 b1 = ((const float4*)src)[1];
        float4 b2 = ((const float4*)src)[2];
        float4 b3 = ((const float4*)src)[3];
        float* dst = &bs[hc][kb];
        ((float4*)dst)[0] = b0; ((float4*)dst)[1] = b1;
        ((float4*)dst)[2] = b2; ((float4*)dst)[3] = b3;
    }
    __syncthreads();
    const int mq  = tid & 3;
    const int hcp = tid >> 2;
    float acc[4] = {0.f, 0.f, 0.f, 0.f};
    #pragma unroll
    for (int r4 = 0; r4 < 16; ++r4) {
        float4 b4  = *(const float4*)&bs[hcp][4*r4];
        float4 h0v = *(const float4*)&hT[4*r4+0][4*mq];
        float4 h1v = *(const float4*)&hT[4*r4+1][4*mq];
        float4 h2v = *(const float4*)&hT[4*r4+2][4*mq];
        float4 h3v = *(const float4*)&hT[4*r4+3][4*mq];
        acc[0] += b4.x*h0v.x + b4.y*h1v.x + b4.z*h2v.x + b4.w*h3v.x;
        acc[1] += b4.x*h0v.y + b4.y*h1v.y + b4.z*h2v.y + b4.w*h3v.y;
        acc[2] += b4.x*h0v.z + b4.y*h1v.z + b4.z*h2v.z + b4.w*h3v.z;
        acc[3] += b4.x*h0v.w + b4.y*h1v.w + b4.z*h2v.w + b4.w*h3v.w;
    }
    #pragma unroll
    for (int j = 0; j < 4; ++j) {
        const int m = 4*mq + j;
        const int t = tids[m];
        if (t >= 0) xbuf[(size_t)t*HNUM + hc0 + hcp] = cof[m] * acc[j];
    }
}

// ---------------------------------------------------------------------------
extern "C" void kernel_launch(void* const* d_in, const int* in_sizes, int n_in,
                              void* d_out, int out_size, void* d_ws, size_t ws_size,
                              hipStream_t stream)
{
    (void)in_sizes; (void)n_in; (void)out_size; (void)ws_size;
    const float* hs    = (const float*)d_in[0];   // [9][T][H]
    const float* gates = (const float*)d_in[1];   // [8]
    const float* A     = (const float*)d_in[2];   // [L][E][R][H]
    const float* Bm    = (const float*)d_in[3];   // [L][E][H][R]
    const float* gw    = (const float*)d_in[4];   // [L][E][H]
    float* xbuf = (float*)d_out;                  // doubles as the x buffer

    // workspace layout (~4.6 MB)
    int*   perm_all = (int*)d_ws;                 // L*PADT
    int*   cnt_all  = perm_all + LNUM*PADT;       // L*E
    int*   ctr_all  = cnt_all + LNUM*ENUM;        // L*E
    int*   g_idx    = ctr_all + LNUM*ENUM;        // T
    float* coefp    = (float*)(g_idx + TNUM);     // T
    float* hbuf     = coefp + TNUM;               // 2*PADT*R floats

    hipMemsetAsync(perm_all, 0xFF, sizeof(int)*(size_t)LNUM*PADT, stream);
    hipMemsetAsync(cnt_all, 0, sizeof(int)*(size_t)2*LNUM*ENUM, stream);

    for (int i = 0; i < LNUM; ++i) {
        const float* xsrc = (i == 0) ? hs : (const float*)xbuf;
        // h_x for iteration i is hidden_states[max(i,1)] (hs[8] is never used)
        const float* hxp  = hs + (size_t)SLICE * (i < 1 ? 1 : i);
        const float* gw_l = gw + (size_t)i*ENUM*HNUM;
        const float* A_l  = A  + (size_t)i*ENUM*RNUM*HNUM;
        const float* B_l  = Bm + (size_t)i*ENUM*HNUM*RNUM;
        int* cnt  = cnt_all + i*ENUM;
        int* ctr  = ctr_all + i*ENUM;
        int* perm = perm_all + i*PADT;
        hipLaunchKernelGGL(mix_gate_kernel, dim3(TNUM/M1), dim3(256), 0, stream,
                           xsrc, hxp, gates, i, gw_l, xbuf, g_idx, coefp, cnt);
        hipLaunchKernelGGL(scatter_kernel, dim3(TNUM/256), dim3(256), 0, stream,
                           g_idx, cnt, ctr, perm);
        hipLaunchKernelGGL(gemmA_kernel, dim3((PADT/M2)*2), dim3(256), 0, stream,
                           xbuf, A_l, perm, g_idx, hbuf);
        hipLaunchKernelGGL(gemmB_kernel, dim3((PADT/M2)*32), dim3(256), 0, stream,
                           hbuf, B_l, perm, g_idx, coefp, xbuf);
    }
}

// Round 2
// 2510.956 us; speedup vs baseline: 1.8153x; 1.8153x over previous
//
#include <hip/hip_runtime.h>
#include <math.h>

// Problem constants (from reference)
#define LNUM 8
#define ENUM 8
#define RNUM 64
#define HNUM 2048
#define TNUM 8192                    // BSZ*SEQ
#define SLICE (TNUM*HNUM)            // one hidden_states slice
#define M1 16                        // tokens per block, mix/gate kernel
#define MT 64                        // tokens per GEMM tile (expert-uniform)
#define PADT2 (TNUM + ENUM*MT)       // 8704: per-expert segments padded to MT
#define KSNUM 4                      // gemmA K-split
#define KPB (HNUM/KSNUM)             // 512 K per gemmA block
#define LSTR 72                      // LDS row stride (elems): 144B = 16B-aligned, 2-way banks (free)
#define NAW (LNUM*ENUM*RNUM*HNUM)    // A elems = Bm elems = 8388608

typedef float v4f    __attribute__((ext_vector_type(4)));
typedef short short8 __attribute__((ext_vector_type(8)));

// --------------------------- bf16 split helpers ----------------------------
__device__ __forceinline__ unsigned bf16_rne_u(float f) {
    unsigned u = __float_as_uint(f);
    return (u + 0x7FFFu + ((u >> 16) & 1u)) >> 16;
}
__device__ __forceinline__ void split2(float f, unsigned short& h, unsigned short& l) {
    unsigned hu = bf16_rne_u(f);
    float hf = __uint_as_float(hu << 16);
    h = (unsigned short)hu;
    l = (unsigned short)bf16_rne_u(f - hf);
}

// ---------------------------------------------------------------------------
// Kernel 0 (once): split A and Bm fp32 weights into bf16 hi/lo planes.
// ---------------------------------------------------------------------------
__global__ __launch_bounds__(256) void prep_split_kernel(
    const float* __restrict__ A, const float* __restrict__ Bm,
    unsigned short* __restrict__ Ah, unsigned short* __restrict__ Al,
    unsigned short* __restrict__ Bh, unsigned short* __restrict__ Bl)
{
    const int i = blockIdx.x * 256 + threadIdx.x;     // float4 index
    const int na4 = NAW / 4;
    const float4* src; unsigned short *dh, *dl; int off;
    if (i < na4) { src = (const float4*)A;  dh = Ah; dl = Al; off = i; }
    else         { src = (const float4*)Bm; dh = Bh; dl = Bl; off = i - na4; }
    float4 v = src[off];
    unsigned short h0,l0,h1,l1,h2,l2,h3,l3;
    split2(v.x,h0,l0); split2(v.y,h1,l1); split2(v.z,h2,l2); split2(v.w,h3,l3);
    *(ushort4*)(dh + 4*(size_t)off) = make_ushort4(h0,h1,h2,h3);
    *(ushort4*)(dl + 4*(size_t)off) = make_ushort4(l0,l1,l2,l3);
}

// ---------------------------------------------------------------------------
// Kernel 1: x = z*x + (1-z)*h_x; gate logits (double-reduced), softmax top-1.
// (unchanged from R1 — validated)
// ---------------------------------------------------------------------------
__global__ __launch_bounds__(256) void mix_gate_kernel(
    const float* __restrict__ xsrc, const float* __restrict__ hx,
    const float* __restrict__ gates, int layer,
    const float* __restrict__ gw,
    float* __restrict__ xbuf, int* __restrict__ g_idx,
    float* __restrict__ coefp, int* __restrict__ cnt)
{
    __shared__ double wred[4][ENUM];
    const int tid  = threadIdx.x;
    const int wave = tid >> 6, lane = tid & 63;
    const float gv = gates[layer];
    const float z  = 1.0f / (1.0f + expf(-gv));
    const float zo = 1.0f - z;
    const float4* gw4 = (const float4*)gw;

    for (int m = 0; m < M1; ++m) {
        const int t = blockIdx.x * M1 + m;
        const size_t b4 = (size_t)t * (HNUM/4);
        float4 xa0 = ((const float4*)xsrc)[b4 + tid];
        float4 xa1 = ((const float4*)xsrc)[b4 + tid + 256];
        float4 xb0 = ((const float4*)hx)[b4 + tid];
        float4 xb1 = ((const float4*)hx)[b4 + tid + 256];
        float4 v0, v1;
        v0.x = z*xa0.x + zo*xb0.x;  v0.y = z*xa0.y + zo*xb0.y;
        v0.z = z*xa0.z + zo*xb0.z;  v0.w = z*xa0.w + zo*xb0.w;
        v1.x = z*xa1.x + zo*xb1.x;  v1.y = z*xa1.y + zo*xb1.y;
        v1.z = z*xa1.z + zo*xb1.z;  v1.w = z*xa1.w + zo*xb1.w;
        ((float4*)xbuf)[b4 + tid]       = v0;
        ((float4*)xbuf)[b4 + tid + 256] = v1;

        double dl[ENUM];
        #pragma unroll
        for (int e = 0; e < ENUM; ++e) {
            float4 g0 = gw4[e*(HNUM/4) + tid];
            float4 g1 = gw4[e*(HNUM/4) + tid + 256];
            float pl = v0.x*g0.x + v0.y*g0.y + v0.z*g0.z + v0.w*g0.w
                     + v1.x*g1.x + v1.y*g1.y + v1.z*g1.z + v1.w*g1.w;
            dl[e] = (double)pl;
        }
        #pragma unroll
        for (int off = 32; off >= 1; off >>= 1) {
            #pragma unroll
            for (int e = 0; e < ENUM; ++e)
                dl[e] += __shfl_down(dl[e], off, 64);
        }
        if (lane == 0) {
            #pragma unroll
            for (int e = 0; e < ENUM; ++e) wred[wave][e] = dl[e];
        }
        __syncthreads();
        if (tid == 0) {
            double lg[ENUM];
            #pragma unroll
            for (int e = 0; e < ENUM; ++e)
                lg[e] = wred[0][e] + wred[1][e] + wred[2][e] + wred[3][e];
            int g = 0; double mx = lg[0];
            #pragma unroll
            for (int e = 1; e < ENUM; ++e) if (lg[e] > mx) { mx = lg[e]; g = e; }
            double s = 0.0;
            #pragma unroll
            for (int e = 0; e < ENUM; ++e) s += exp(lg[e] - mx);
            g_idx[t] = g;
            coefp[t] = (float)(0.5 / s);
            atomicAdd(&cnt[g], 1);
        }
        __syncthreads();
    }
}

// ---------------------------------------------------------------------------
// Kernel 2: scatter tokens into expert-contiguous segments padded to MT=64.
// ---------------------------------------------------------------------------
__global__ __launch_bounds__(256) void scatter_kernel(
    const int* __restrict__ g_idx, const int* __restrict__ cnt,
    int* __restrict__ ctr, int* __restrict__ perm)
{
    const int t = blockIdx.x * 256 + threadIdx.x;
    const int g = g_idx[t];
    int base = 0;
    #pragma unroll
    for (int e = 0; e < ENUM; ++e) {
        int padded = (cnt[e] + (MT - 1)) & ~(MT - 1);
        if (e < g) base += padded;
    }
    const int pos = base + atomicAdd(&ctr[g], 1);
    perm[pos] = t;
}

// expert for this tile from padded prefix sums; returns -1 if tile is all-pad
__device__ __forceinline__ int tile_expert(const int* cnt, int pos0, int* total_out) {
    int e = -1, total = 0;
    #pragma unroll
    for (int ee = 0; ee < ENUM; ++ee) {
        int padded = (cnt[ee] + (MT - 1)) & ~(MT - 1);
        if (pos0 >= total && pos0 < total + padded) e = ee;
        total += padded;
    }
    *total_out = total;
    return e;
}

// ---------------------------------------------------------------------------
// Kernel 3: gemmA (MFMA): hpart[ks][pos][r] = A_e[r][ksK:ksK+512] . x[t][...]
// Tile: 64 tokens x 64 r, K=512 per block. 4-pass hi/lo bf16 split (exact to
// 2^-18 rel). mfma_f32_16x16x32_bf16; layouts per m89/m120.
// ---------------------------------------------------------------------------
__global__ __launch_bounds__(256) void gemmA_mfma(
    const float* __restrict__ xbuf,
    const unsigned short* __restrict__ Ah, const unsigned short* __restrict__ Al,
    const int* __restrict__ perm, const int* __restrict__ cnt,
    float* __restrict__ hpart)
{
    __shared__ int tids[MT];
    __shared__ __align__(16) unsigned short xh[MT][LSTR], xl[MT][LSTR];
    __shared__ __align__(16) unsigned short wh[RNUM][LSTR], wl[RNUM][LSTR];
    const int bx = blockIdx.x;
    const int mt = bx >> 2, ks = bx & 3;
    const int pos0 = mt * MT;
    int total;
    const int e = tile_expert(cnt, pos0, &total);
    if (pos0 >= total) return;
    const int tid = threadIdx.x;
    if (tid < MT) tids[tid] = perm[pos0 + tid];
    __syncthreads();

    const unsigned short* Whg = Ah + (size_t)e * RNUM * HNUM;
    const unsigned short* Wlg = Al + (size_t)e * RNUM * HNUM;
    const int lane = tid & 63, wave = tid >> 6;
    const int m0 = wave * 16;
    const int fr = lane & 15;               // frag row (m or n)
    const int kq = (lane >> 4) * 8;         // frag k offset
    v4f acc[4];
    #pragma unroll
    for (int nb = 0; nb < 4; ++nb) acc[nb] = (v4f){0.f, 0.f, 0.f, 0.f};

    for (int ch = 0; ch < KPB/64; ++ch) {
        const int kbase = ks*KPB + ch*64;
        // global reads (regs only)
        float4 xv[4];
        #pragma unroll
        for (int q = 0; q < 4; ++q) {
            int idx = q*256 + tid, sm = idx >> 4, sk4 = idx & 15;
            int t = tids[sm];
            xv[q] = (t >= 0) ? *(const float4*)(xbuf + (size_t)t*HNUM + kbase + 4*sk4)
                             : make_float4(0.f, 0.f, 0.f, 0.f);
        }
        uint4 wvh[2], wvl[2];
        #pragma unroll
        for (int q = 0; q < 2; ++q) {
            int idx = q*256 + tid, sr = idx >> 3, sk8 = idx & 7;
            wvh[q] = *(const uint4*)(Whg + (size_t)sr*HNUM + kbase + 8*sk8);
            wvl[q] = *(const uint4*)(Wlg + (size_t)sr*HNUM + kbase + 8*sk8);
        }
        __syncthreads();   // prev-chunk compute done
        #pragma unroll
        for (int q = 0; q < 4; ++q) {
            int idx = q*256 + tid, sm = idx >> 4, sk4 = idx & 15;
            unsigned short h0,l0,h1,l1,h2,l2,h3,l3;
            split2(xv[q].x,h0,l0); split2(xv[q].y,h1,l1);
            split2(xv[q].z,h2,l2); split2(xv[q].w,h3,l3);
            *(ushort4*)&xh[sm][4*sk4] = make_ushort4(h0,h1,h2,h3);
            *(ushort4*)&xl[sm][4*sk4] = make_ushort4(l0,l1,l2,l3);
        }
        #pragma unroll
        for (int q = 0; q < 2; ++q) {
            int idx = q*256 + tid, sr = idx >> 3, sk8 = idx & 7;
            *(uint4*)&wh[sr][8*sk8] = wvh[q];
            *(uint4*)&wl[sr][8*sk8] = wvl[q];
        }
        __syncthreads();
        #pragma unroll
        for (int ki = 0; ki < 2; ++ki) {
            const int kk = ki*32 + kq;
            short8 ah = *(const short8*)&xh[m0 + fr][kk];
            short8 al = *(const short8*)&xl[m0 + fr][kk];
            #pragma unroll
            for (int nb = 0; nb < 4; ++nb) {
                short8 bh = *(const short8*)&wh[nb*16 + fr][kk];
                short8 bl = *(const short8*)&wl[nb*16 + fr][kk];
                acc[nb] = __builtin_amdgcn_mfma_f32_16x16x32_bf16(ah, bh, acc[nb], 0, 0, 0);
                acc[nb] = __builtin_amdgcn_mfma_f32_16x16x32_bf16(ah, bl, acc[nb], 0, 0, 0);
                acc[nb] = __builtin_amdgcn_mfma_f32_16x16x32_bf16(al, bh, acc[nb], 0, 0, 0);
                acc[nb] = __builtin_amdgcn_mfma_f32_16x16x32_bf16(al, bl, acc[nb], 0, 0, 0);
            }
        }
    }
    // epilogue: C/D col=lane&15 (r in nb), row=quad*4+reg (m)
    float* hp = hpart + ((size_t)ks*PADT2 + pos0) * RNUM;
    const int row0 = (lane >> 4) * 4;
    #pragma unroll
    for (int nb = 0; nb < 4; ++nb)
        #pragma unroll
        for (int reg = 0; reg < 4; ++reg)
            hp[(size_t)(m0 + row0 + reg)*RNUM + nb*16 + fr] = acc[nb][reg];
}

// ---------------------------------------------------------------------------
// Kernel 4: reduce 4 K-split h partials, split to bf16 hi/lo planes.
// ---------------------------------------------------------------------------
__global__ __launch_bounds__(256) void hreduce_kernel(
    const float* __restrict__ hpart,
    unsigned short* __restrict__ hh, unsigned short* __restrict__ hl)
{
    const int i = blockIdx.x * 256 + threadIdx.x;     // float4 index
    const int stride4 = PADT2 * RNUM / 4;
    const float4* p = (const float4*)hpart;
    float4 a = p[i], b = p[i + stride4], c = p[i + 2*stride4], d = p[i + 3*stride4];
    float4 s = make_float4(a.x+b.x+c.x+d.x, a.y+b.y+c.y+d.y,
                           a.z+b.z+c.z+d.z, a.w+b.w+c.w+d.w);
    unsigned short h0,l0,h1,l1,h2,l2,h3,l3;
    split2(s.x,h0,l0); split2(s.y,h1,l1); split2(s.z,h2,l2); split2(s.w,h3,l3);
    *(ushort4*)(hh + 4*(size_t)i) = make_ushort4(h0,h1,h2,h3);
    *(ushort4*)(hl + 4*(size_t)i) = make_ushort4(l0,l1,l2,l3);
}

// ---------------------------------------------------------------------------
// Kernel 5: gemmB (MFMA): y[t][hc] = coef[t] * sum_r h[pos][r]*B_e[hc][r].
// Tile: 64 tokens x 128 hc, K=64. Same 4-pass split.
// ---------------------------------------------------------------------------
__global__ __launch_bounds__(256) void gemmB_mfma(
    const unsigned short* __restrict__ hh_g, const unsigned short* __restrict__ hl_g,
    const unsigned short* __restrict__ Bh, const unsigned short* __restrict__ Bl,
    const int* __restrict__ perm, const int* __restrict__ cnt,
    const float* __restrict__ coefp, float* __restrict__ xbuf)
{
    __shared__ int   tids[MT];
    __shared__ float cof[MT];
    __shared__ __align__(16) unsigned short hh[MT][LSTR],  hl[MT][LSTR];
    __shared__ __align__(16) unsigned short bh[128][LSTR], bl[128][LSTR];
    const int bx = blockIdx.x;
    const int mt = bx >> 4, hcb = bx & 15;
    const int pos0 = mt * MT, hc0 = hcb * 128;
    int total;
    const int e = tile_expert(cnt, pos0, &total);
    if (pos0 >= total) return;
    const int tid = threadIdx.x;
    if (tid < MT) {
        int t = perm[pos0 + tid];
        tids[tid] = t;
        cof[tid] = (t >= 0) ? coefp[t] : 0.0f;
    }
    // stage h (already permuted order): 2 uint4 per plane per thread
    #pragma unroll
    for (int q = 0; q < 2; ++q) {
        int idx = q*256 + tid, sm = idx >> 3, sk8 = idx & 7;
        uint4 vh = *(const uint4*)(hh_g + (size_t)(pos0 + sm)*RNUM + 8*sk8);
        uint4 vl = *(const uint4*)(hl_g + (size_t)(pos0 + sm)*RNUM + 8*sk8);
        *(uint4*)&hh[sm][8*sk8] = vh;
        *(uint4*)&hl[sm][8*sk8] = vl;
    }
    // stage B: rows are hc, cols r; 4 uint4 per plane per thread
    const unsigned short* Bhg = Bh + (size_t)e * HNUM * RNUM;
    const unsigned short* Blg = Bl + (size_t)e * HNUM * RNUM;
    #pragma unroll
    for (int q = 0; q < 4; ++q) {
        int idx = q*256 + tid, shc = idx >> 3, sk8 = idx & 7;
        uint4 vh = *(const uint4*)(Bhg + (size_t)(hc0 + shc)*RNUM + 8*sk8);
        uint4 vl = *(const uint4*)(Blg + (size_t)(hc0 + shc)*RNUM + 8*sk8);
        *(uint4*)&bh[shc][8*sk8] = vh;
        *(uint4*)&bl[shc][8*sk8] = vl;
    }
    __syncthreads();

    const int lane = tid & 63, wave = tid >> 6;
    const int m0 = wave * 16;
    const int fr = lane & 15;
    const int kq = (lane >> 4) * 8;
    v4f acc[8];
    #pragma unroll
    for (int nb = 0; nb < 8; ++nb) acc[nb] = (v4f){0.f, 0.f, 0.f, 0.f};

    #pragma unroll
    for (int ki = 0; ki < 2; ++ki) {
        const int kk = ki*32 + kq;
        short8 ah = *(const short8*)&hh[m0 + fr][kk];
        short8 al = *(const short8*)&hl[m0 + fr][kk];
        #pragma unroll
        for (int nb = 0; nb < 8; ++nb) {
            short8 wbh = *(const short8*)&bh[nb*16 + fr][kk];
            short8 wbl = *(const short8*)&bl[nb*16 + fr][kk];
            acc[nb] = __builtin_amdgcn_mfma_f32_16x16x32_bf16(ah, wbh, acc[nb], 0, 0, 0);
            acc[nb] = __builtin_amdgcn_mfma_f32_16x16x32_bf16(ah, wbl, acc[nb], 0, 0, 0);
            acc[nb] = __builtin_amdgcn_mfma_f32_16x16x32_bf16(al, wbh, acc[nb], 0, 0, 0);
            acc[nb] = __builtin_amdgcn_mfma_f32_16x16x32_bf16(al, wbl, acc[nb], 0, 0, 0);
        }
    }
    const int row0 = (lane >> 4) * 4;
    #pragma unroll
    for (int nb = 0; nb < 8; ++nb) {
        #pragma unroll
        for (int reg = 0; reg < 4; ++reg) {
            const int m = m0 + row0 + reg;
            const int t = tids[m];
            if (t >= 0)
                xbuf[(size_t)t*HNUM + hc0 + nb*16 + fr] = cof[m] * acc[nb][reg];
        }
    }
}

// ---------------------------------------------------------------------------
extern "C" void kernel_launch(void* const* d_in, const int* in_sizes, int n_in,
                              void* d_out, int out_size, void* d_ws, size_t ws_size,
                              hipStream_t stream)
{
    (void)in_sizes; (void)n_in; (void)out_size; (void)ws_size;
    const float* hs    = (const float*)d_in[0];   // [9][T][H]
    const float* gates = (const float*)d_in[1];   // [8]
    const float* A     = (const float*)d_in[2];   // [L][E][R][H]
    const float* Bm    = (const float*)d_in[3];   // [L][E][H][R]
    const float* gw    = (const float*)d_in[4];   // [L][E][H]
    float* xbuf = (float*)d_out;                  // doubles as the x buffer

    // workspace layout (~78.5 MB), all offsets 16B-aligned
    char* w = (char*)d_ws;
    int*   perm_all = (int*)w;                 w += sizeof(int)*(size_t)LNUM*PADT2;
    int*   cnt_all  = (int*)w;                 w += sizeof(int)*LNUM*ENUM;
    int*   ctr_all  = (int*)w;                 w += sizeof(int)*LNUM*ENUM;
    int*   g_idx    = (int*)w;                 w += sizeof(int)*TNUM;
    float* coefp    = (float*)w;               w += sizeof(float)*TNUM;
    float* hpart    = (float*)w;               w += sizeof(float)*(size_t)KSNUM*PADT2*RNUM;
    unsigned short* hh_g = (unsigned short*)w; w += sizeof(short)*(size_t)PADT2*RNUM;
    unsigned short* hl_g = (unsigned short*)w; w += sizeof(short)*(size_t)PADT2*RNUM;
    unsigned short* Ah = (unsigned short*)w;   w += sizeof(short)*(size_t)NAW;
    unsigned short* Al = (unsigned short*)w;   w += sizeof(short)*(size_t)NAW;
    unsigned short* Bh = (unsigned short*)w;   w += sizeof(short)*(size_t)NAW;
    unsigned short* Bl = (unsigned short*)w;   w += sizeof(short)*(size_t)NAW;

    hipMemsetAsync(perm_all, 0xFF, sizeof(int)*(size_t)LNUM*PADT2, stream);
    hipMemsetAsync(cnt_all, 0, sizeof(int)*(size_t)2*LNUM*ENUM, stream);
    hipLaunchKernelGGL(prep_split_kernel, dim3(2*NAW/4/256), dim3(256), 0, stream,
                       A, Bm, Ah, Al, Bh, Bl);

    for (int i = 0; i < LNUM; ++i) {
        const float* xsrc = (i == 0) ? hs : (const float*)xbuf;
        const float* hxp  = hs + (size_t)SLICE * (i < 1 ? 1 : i);
        const float* gw_l = gw + (size_t)i*ENUM*HNUM;
        int* cnt  = cnt_all + i*ENUM;
        int* ctr  = ctr_all + i*ENUM;
        int* perm = perm_all + i*PADT2;
        const unsigned short* Ah_l = Ah + (size_t)i*ENUM*RNUM*HNUM;
        const unsigned short* Al_l = Al + (size_t)i*ENUM*RNUM*HNUM;
        const unsigned short* Bh_l = Bh + (size_t)i*ENUM*HNUM*RNUM;
        const unsigned short* Bl_l = Bl + (size_t)i*ENUM*HNUM*RNUM;

        hipLaunchKernelGGL(mix_gate_kernel, dim3(TNUM/M1), dim3(256), 0, stream,
                           xsrc, hxp, gates, i, gw_l, xbuf, g_idx, coefp, cnt);
        hipLaunchKernelGGL(scatter_kernel, dim3(TNUM/256), dim3(256), 0, stream,
                           g_idx, cnt, ctr, perm);
        hipLaunchKernelGGL(gemmA_mfma, dim3((PADT2/MT)*KSNUM), dim3(256), 0, stream,
                           xbuf, Ah_l, Al_l, perm, cnt, hpart);
        hipLaunchKernelGGL(hreduce_kernel, dim3(PADT2*RNUM/4/256), dim3(256), 0, stream,
                           hpart, hh_g, hl_g);
        hipLaunchKernelGGL(gemmB_mfma, dim3((PADT2/MT)*16), dim3(256), 0, stream,
                           hh_g, hl_g, Bh_l, Bl_l, perm, cnt, coefp, xbuf);
    }
}